// Round 8
// baseline (276.526 us; speedup 1.0000x reference)
//
#include <hip/hip_runtime.h>
#include <hip/hip_bf16.h>

// GCNConv: out = D^-1/2 (A+I) D^-1/2 (X W) + b
// N=100000, E=1600000, IN=128, OUT=64. edge_index int32, [row(E) | col(E)].
//
// Pipeline v16 — direct-scatter CSR (place/bucket_sort/pairs eliminated):
//   0. prep:        W fp32 [k][n] -> wbt bf16 [n][k]; nodecnt = 0; csr = n
//                   (sentinel prefill, uint4); ovc = 0
//   1. place2:      e-parallel: pos = atomicAdd(&nodecnt[col],1);
//                   pos<32 -> csr[col*32+pos] = row; else global ov list.
//                   (replaces LDS-hist place + in-LDS bucket_sort: ~55-60us of
//                   pairs round-trip + 3.2M LDS atomics -> 1.6M L2 atomics)
//   2. gemm:        MFMA 16x16x32 bf16; hp = (rsqrt(nodecnt+1)*x) @ W; row n=0
//   3. aggregate:   v15 body: wave/node, iv=csr line, guarded dwordx4 gathers,
//                   dinv/deg from nodecnt inline, overflow via ballot scan.

#define IN_CH 128
#define OUT_CH 64
#define SLOTS 32            // fixed csr slots per node
#define OVCAP 256           // global overflow capacity (deg>32 excess edges)
#define XSTR 136            // bf16 LDS row stride: 272B -> conflict-free b128

typedef short bf16x8 __attribute__((ext_vector_type(8)));
typedef float f32x4  __attribute__((ext_vector_type(4)));

__device__ __forceinline__ unsigned short f2b(float f) {   // RNE fp32->bf16
    unsigned int u = __float_as_uint(f);
    return (unsigned short)((u + 0x7FFFu + ((u >> 16) & 1u)) >> 16);
}

__device__ __forceinline__ float blo(unsigned u) { return __uint_as_float(u << 16); }
__device__ __forceinline__ float bhi(unsigned u) { return __uint_as_float(u & 0xFFFF0000u); }

// ---------------- 0: prep — wbt, nodecnt=0, csr sentinel fill, ovc=0 --------
// grid covers n*8 uint4 sentinel stores (n*32 ints); wbt/nodecnt piggyback.
__global__ __launch_bounds__(256) void prep_kernel(const float* __restrict__ W,
                                                   unsigned short* __restrict__ wbt,
                                                   int* __restrict__ nodecnt,
                                                   int4* __restrict__ csr4,
                                                   int* __restrict__ ovc, int n) {
    int t = blockIdx.x * 256 + threadIdx.x;
    if (t < n * 8) csr4[t] = make_int4(n, n, n, n);
    if (t < IN_CH * OUT_CH) {
        int k = t >> 6, nn = t & 63;
        wbt[nn * IN_CH + k] = f2b(W[t]);
    }
    if (t < n) nodecnt[t] = 0;
    if (t == 0) *ovc = 0;
}

// ---------------- 1: place2 — direct scatter into fixed-32 csr --------------
__global__ __launch_bounds__(256) void place2_kernel(const int* __restrict__ row,
                                                     const int* __restrict__ col,
                                                     int* __restrict__ nodecnt,
                                                     int* __restrict__ csr,
                                                     int* __restrict__ ovn,
                                                     int* __restrict__ ovr,
                                                     int* __restrict__ ovc, int E) {
    int t = blockIdx.x * 256 + threadIdx.x;
    int e = t * 4;
    if (e >= E) return;              // E % 4 == 0
    int4 c4 = *(const int4*)(col + e);
    int4 r4 = *(const int4*)(row + e);
    #define PUT(CN, RN)                                                   \
        { int node = (CN), src = (RN);                                    \
          int pos = atomicAdd(&nodecnt[node], 1);                         \
          if (pos < SLOTS) csr[node * SLOTS + pos] = src;                 \
          else { int o = atomicAdd(ovc, 1);                               \
                 if (o < OVCAP) { ovn[o] = node; ovr[o] = src; } } }
    PUT(c4.x, r4.x) PUT(c4.y, r4.y) PUT(c4.z, r4.z) PUT(c4.w, r4.w)
    #undef PUT
}

// ---------------- 2: MFMA GEMM  hp_bf16 = (dinv*x) @ W  (+ zero row n) ------
// 256 thr = 4 waves; 64-row tile; wave w does rows w*16..w*16+15 x all 64 cols.
__global__ __launch_bounds__(256) void gemm_kernel(
    const float* __restrict__ x, const unsigned short* __restrict__ wbt,
    const int* __restrict__ nodecnt, unsigned short* __restrict__ hpb, int n)
{
    __shared__ __align__(16) unsigned short xl[64 * XSTR];  // 17408 B
    __shared__ __align__(16) unsigned short wl[64 * XSTR];  // W^T: [n][k]

    int tid  = threadIdx.x;
    int row0 = blockIdx.x * 64;

    {
        const uint4* src = (const uint4*)wbt;
        #pragma unroll
        for (int i = 0; i < 4; ++i) {
            int flat = tid + i * 256;
            int nn = flat >> 4, c = flat & 15;
            *(uint4*)(wl + nn * XSTR + c * 8) = src[flat];
        }
    }
    #pragma unroll
    for (int i = 0; i < 4; ++i) {
        int r  = (tid >> 4) + i * 16;
        int c  = tid & 15;
        int gr = row0 + r;
        float4 v0 = make_float4(0.f,0.f,0.f,0.f), v1 = v0;
        float d = 0.f;
        if (gr < n) {
            d = rsqrtf((float)(nodecnt[gr] + 1));     // +1 self loop
            const float4* xr = (const float4*)(x + (size_t)gr * IN_CH);
            v0 = xr[c * 2]; v1 = xr[c * 2 + 1];
        }
        uint4 p;
        p.x = ((unsigned)f2b(v0.y * d) << 16) | f2b(v0.x * d);
        p.y = ((unsigned)f2b(v0.w * d) << 16) | f2b(v0.z * d);
        p.z = ((unsigned)f2b(v1.y * d) << 16) | f2b(v1.x * d);
        p.w = ((unsigned)f2b(v1.w * d) << 16) | f2b(v1.z * d);
        *(uint4*)(xl + r * XSTR + c * 8) = p;
    }
    __syncthreads();

    int lane = tid & 63, w = tid >> 6;
    int mrow = lane & 15;
    int g    = lane >> 4;

    f32x4 acc0 = {0,0,0,0}, acc1 = {0,0,0,0}, acc2 = {0,0,0,0}, acc3 = {0,0,0,0};
    const unsigned short* xbase = xl + (w * 16 + mrow) * XSTR + g * 8;
    const unsigned short* wbase = wl + mrow * XSTR + g * 8;

    #pragma unroll
    for (int k4 = 0; k4 < 4; ++k4) {
        bf16x8 a  = *(const bf16x8*)(xbase + k4 * 32);
        bf16x8 b0 = *(const bf16x8*)(wbase +             k4 * 32);
        bf16x8 b1 = *(const bf16x8*)(wbase + 16 * XSTR + k4 * 32);
        bf16x8 b2 = *(const bf16x8*)(wbase + 32 * XSTR + k4 * 32);
        bf16x8 b3 = *(const bf16x8*)(wbase + 48 * XSTR + k4 * 32);
        acc0 = __builtin_amdgcn_mfma_f32_16x16x32_bf16(a, b0, acc0, 0, 0, 0);
        acc1 = __builtin_amdgcn_mfma_f32_16x16x32_bf16(a, b1, acc1, 0, 0, 0);
        acc2 = __builtin_amdgcn_mfma_f32_16x16x32_bf16(a, b2, acc2, 0, 0, 0);
        acc3 = __builtin_amdgcn_mfma_f32_16x16x32_bf16(a, b3, acc3, 0, 0, 0);
    }
    __syncthreads();   // done reading xl; reuse it for the C tile

    {
        int cm = g * 4;
        #pragma unroll
        for (int r = 0; r < 4; ++r) {
            unsigned short* crow = xl + (w * 16 + cm + r) * XSTR + mrow;
            crow[ 0] = f2b(acc0[r]);
            crow[16] = f2b(acc1[r]);
            crow[32] = f2b(acc2[r]);
            crow[48] = f2b(acc3[r]);
        }
    }
    __syncthreads();
    #pragma unroll
    for (int i = 0; i < 2; ++i) {
        int flat = tid + i * 256;
        int r = flat >> 3, c = flat & 7;
        int gr = row0 + r;
        if (gr <= n) {     // row n = sentinel zero row for padded aggregation
            uint4 v = *(const uint4*)(xl + r * XSTR + c * 8);
            *(uint4*)(hpb + (size_t)gr * OUT_CH + c * 8) = v;
        }
    }
}

// ---------------- 3: aggregate — wave/node, guarded gathers, fixed-32 -------
// lane = (e = edge slot 0..7, c = 16B chunk 0..7).
// iv = csr[wid*32 + (lane&31)] : ONE 128B line; nodecnt/self/ovc issue in
// parallel. Gather g uses rows shfl(iv, g*8+e), guarded by wave-uniform
// rnds = ceil(min(deg,32)/8). Overflow: lane-parallel scan + ballot (~free).
__global__ __launch_bounds__(256) void aggregate_kernel(
    const int* __restrict__ csr, const int* __restrict__ nodecnt,
    const int* __restrict__ ovn, const int* __restrict__ ovr,
    const int* __restrict__ ovc,
    const unsigned short* __restrict__ hpb,
    const float* __restrict__ bias, float* __restrict__ out, int n)
{
    int wid  = (blockIdx.x * 256 + threadIdx.x) >> 6;   // node id
    int lane = threadIdx.x & 63;
    if (wid >= n) return;
    int e   = lane >> 3;
    int c   = lane & 7;
    int l31 = lane & 31;

    const uint4* hp16 = (const uint4*)hpb;   // row = 8 x uint4

    // independent loads — all issue before any dependency:
    int iv  = csr[wid * SLOTS + l31];
    int dg  = nodecnt[wid];
    int oc  = *ovc;
    uint4 sv = hp16[(unsigned)(wid * 8 + c)];           // self-loop chunk (1 line)

    float d = rsqrtf((float)(dg + 1));
    int rnds = (min(dg, SLOTS) + 7) >> 3;               // 0..4, wave-uniform

    float axl=0.f,axh=0.f, ayl=0.f,ayh=0.f, azl=0.f,azh=0.f, awl=0.f,awh=0.f;

    #define GATHER(SRC) \
        { int r_ = __shfl(iv, (SRC));                                            \
          uint4 v_ = hp16[(unsigned)(r_ * 8 + c)];                               \
          axl += blo(v_.x); axh += bhi(v_.x);                                    \
          ayl += blo(v_.y); ayh += bhi(v_.y);                                    \
          azl += blo(v_.z); azh += bhi(v_.z);                                    \
          awl += blo(v_.w); awh += bhi(v_.w); }

    if (rnds > 0) GATHER(     e)
    if (rnds > 1) GATHER( 8 + e)
    if (rnds > 2) GATHER(16 + e)
    if (rnds > 3) GATHER(24 + e)
    #undef GATHER

    if (oc > 0) {                     // deg>32 spill: tiny global list
        oc = min(oc, OVCAP);
        for (int base = 0; base < oc; base += 64) {
            int i  = base + lane;
            int nd = (i < oc) ? ovn[i] : -1;
            int rs = (i < oc) ? ovr[i] : 0;
            unsigned long long mm = __ballot(nd == wid);
            while (mm) {              // ~never taken (only overflowed nodes)
                int bit = __ffsll((long long)mm) - 1;
                mm &= mm - 1;
                int r_ = __shfl(rs, base == 0 ? bit : bit);   // lane index in this 64-group
                uint4 v_ = hp16[(unsigned)(r_ * 8 + c)];
                if (e == 0) {         // count once across the 8 e-slots
                    axl += blo(v_.x); axh += bhi(v_.x);
                    ayl += blo(v_.y); ayh += bhi(v_.y);
                    azl += blo(v_.z); azh += bhi(v_.z);
                    awl += blo(v_.w); awh += bhi(v_.w);
                }
            }
        }
    }

    // reduce across the 8 edge slots (lanes c, c+8, ..., c+56)
    #pragma unroll
    for (int m = 8; m < 64; m <<= 1) {
        axl += __shfl_xor(axl, m); axh += __shfl_xor(axh, m);
        ayl += __shfl_xor(ayl, m); ayh += __shfl_xor(ayh, m);
        azl += __shfl_xor(azl, m); azh += __shfl_xor(azh, m);
        awl += __shfl_xor(awl, m); awh += __shfl_xor(awh, m);
    }

    if (e == 0) {              // lanes 0..7 finalize chunk c = channels 8c..8c+7
        axl += blo(sv.x); axh += bhi(sv.x);
        ayl += blo(sv.y); ayh += bhi(sv.y);
        azl += blo(sv.z); azh += bhi(sv.z);
        awl += blo(sv.w); awh += bhi(sv.w);
        float4 b0 = ((const float4*)bias)[2 * c];
        float4 b1 = ((const float4*)bias)[2 * c + 1];
        float4 o0, o1;
        o0.x = fmaf(d, axl, b0.x); o0.y = fmaf(d, axh, b0.y);
        o0.z = fmaf(d, ayl, b0.z); o0.w = fmaf(d, ayh, b0.w);
        o1.x = fmaf(d, azl, b1.x); o1.y = fmaf(d, azh, b1.y);
        o1.z = fmaf(d, awl, b1.z); o1.w = fmaf(d, awh, b1.w);
        float* op = out + (size_t)wid * OUT_CH + c * 8;
        *(float4*)op       = o0;
        *(float4*)(op + 4) = o1;
    }
}

extern "C" void kernel_launch(void* const* d_in, const int* in_sizes, int n_in,
                              void* d_out, int out_size, void* d_ws, size_t ws_size,
                              hipStream_t stream) {
    const float* x  = (const float*)d_in[0];
    const int*   ei = (const int*)d_in[1];
    const float* W  = (const float*)d_in[2];
    const float* b  = (const float*)d_in[3];
    float*       out = (float*)d_out;

    int n = in_sizes[0] / IN_CH;     // 100000
    int E = in_sizes[1] / 2;         // 1600000
    const int* row = ei;
    const int* col = ei + E;

    // workspace layout (~26 MB of 256 MiB)
    char* ws = (char*)d_ws;
    int*   nodecnt = (int*)ws;  ws += (size_t)n * 4;
    int*   ovc     = (int*)ws;  ws += 256;                 // padded
    int*   ovn     = (int*)ws;  ws += (size_t)OVCAP * 4;
    int*   ovr     = (int*)ws;  ws += (size_t)OVCAP * 4;
    unsigned short* wbt = (unsigned short*)ws; ws += (size_t)IN_CH * OUT_CH * 2;
    ws = (char*)(((uintptr_t)ws + 255) & ~(uintptr_t)255);
    int*   csr     = (int*)ws;  ws += (size_t)n * SLOTS * 4;   // 12.8 MB
    ws = (char*)(((uintptr_t)ws + 255) & ~(uintptr_t)255);
    unsigned short* hpb = (unsigned short*)ws;   // (n+1)*64 bf16 (row n = zeros)

    int prep_blk   = (n * 8 + 255) / 256;        // covers n*8 uint4 sentinel stores
    int place_blk  = (E / 4 + 255) / 256;

    prep_kernel     <<<prep_blk, 256, 0, stream>>>(W, wbt, nodecnt, (int4*)csr, ovc, n);
    place2_kernel   <<<place_blk, 256, 0, stream>>>(row, col, nodecnt, csr, ovn, ovr, ovc, E);
    gemm_kernel     <<<(n + 63) / 64, 256, 0, stream>>>(x, wbt, nodecnt, hpb, n);
    aggregate_kernel<<<((size_t)n * 64 + 255) / 256, 256, 0, stream>>>(csr, nodecnt, ovn, ovr, ovc, hpb, b, out, n);
}

// Round 9
// 232.785 us; speedup vs baseline: 1.1879x; 1.1879x over previous
//
#include <hip/hip_runtime.h>
#include <hip/hip_bf16.h>

// GCNConv: out = D^-1/2 (A+I) D^-1/2 (X W) + b
// N=100000, E=1600000, IN=128, OUT=64. edge_index int32, [row(E) | col(E)].
//
// Pipeline v17 — fused sort+aggregate (csr round-trip eliminated):
//   0. prep:   W fp32 [k][n] -> wbt bf16 [n][k]; cursor[b]=b*PSTRIDE; nodecnt=0
//   1. place:  int4 LDS bucket-hist (+ fire-and-forget global deg atomics — NO
//              return value, so no v16 latency chain) -> span reservation ->
//              scatter pairs at fixed per-bucket stride
//   2. gemm:   MFMA 16x16x32 bf16; hp = (rsqrt(nodecnt+1)*x) @ W; row n = 0
//   3. sortagg (512 thr): in-LDS counting sort into fixed 32 slots/node
//              (sentinel n), then 8 waves x 16 nodes aggregate DIRECTLY from
//              the LDS tile: guarded dwordx4 gathers (v15 body), butterfly,
//              epilogue. Removes csr write(12.8MB)+read(12.8MB)+sentinel
//              prefill + the per-node dependent csr line load + 1 launch.

#define IN_CH 128
#define OUT_CH 64
#define BSHIFT 7            // 128 nodes per bucket
#define BNODES 128
#define MAX_NB 800
#define CH_EDGES 8192       // edges per partition block (2 rounds x 1024 x int4)
#define PSTRIDE 4096        // ints per bucket in pairs (avg 2046, max ~2300)
#define SLOTS 32            // fixed sorted slots per node
#define SORT_CAP (BNODES * SLOTS)   // 4096 ints = 16 KB
#define OVB 256             // per-bucket overflow entries (deg>32 excess)
#define XSTR 136            // bf16 LDS row stride: 272B -> conflict-free b128

typedef short bf16x8 __attribute__((ext_vector_type(8)));
typedef float f32x4  __attribute__((ext_vector_type(4)));

__device__ __forceinline__ unsigned short f2b(float f) {   // RNE fp32->bf16
    unsigned int u = __float_as_uint(f);
    return (unsigned short)((u + 0x7FFFu + ((u >> 16) & 1u)) >> 16);
}

__device__ __forceinline__ float blo(unsigned u) { return __uint_as_float(u << 16); }
__device__ __forceinline__ float bhi(unsigned u) { return __uint_as_float(u & 0xFFFF0000u); }

// ---------------- 0: prep — wbt, cursor init, nodecnt = 0 ----------------
__global__ __launch_bounds__(256) void prep_kernel(const float* __restrict__ W,
                                                   unsigned short* __restrict__ wbt,
                                                   int* __restrict__ cursor,
                                                   int* __restrict__ nodecnt,
                                                   int NB, int n) {
    int t = blockIdx.x * 256 + threadIdx.x;
    if (t < IN_CH * OUT_CH) {
        int k = t >> 6, nn = t & 63;
        wbt[nn * IN_CH + k] = f2b(W[t]);
    }
    if (t < NB) cursor[t] = t * PSTRIDE;
    if (t < n) nodecnt[t] = 0;
}

// ---------------- 1: place — int4 hist + deg atomics + reservation ----------
__global__ __launch_bounds__(1024) void place_kernel(const int* __restrict__ row,
                                                     const int* __restrict__ col,
                                                     int* __restrict__ cursor,
                                                     int* __restrict__ nodecnt,
                                                     int* __restrict__ pairs,
                                                     int E, int NB) {
    __shared__ int h[MAX_NB];
    int tid = threadIdx.x;
    for (int i = tid; i < NB; i += 1024) h[i] = 0;
    __syncthreads();
    int e0 = blockIdx.x * CH_EDGES;
    // E % 4 == 0 and e is 4-aligned, so (e < E) <=> (e+3 < E)
    #pragma unroll
    for (int r1 = 0; r1 < CH_EDGES / 4096; ++r1) {
        int e = e0 + (r1 * 1024 + tid) * 4;
        if (e < E) {
            int4 c4 = *(const int4*)(col + e);
            atomicAdd(&h[c4.x >> BSHIFT], 1);
            atomicAdd(&h[c4.y >> BSHIFT], 1);
            atomicAdd(&h[c4.z >> BSHIFT], 1);
            atomicAdd(&h[c4.w >> BSHIFT], 1);
            // per-node degree: fire-and-forget (no return -> no latency chain)
            atomicAdd(&nodecnt[c4.x], 1);
            atomicAdd(&nodecnt[c4.y], 1);
            atomicAdd(&nodecnt[c4.z], 1);
            atomicAdd(&nodecnt[c4.w], 1);
        }
    }
    __syncthreads();
    // reserve a contiguous span per (bucket, block); h[i] becomes local cursor
    for (int i = tid; i < NB; i += 1024) {
        int c = h[i];
        if (c) h[i] = atomicAdd(&cursor[i], c);
    }
    __syncthreads();
    #pragma unroll
    for (int r2 = 0; r2 < CH_EDGES / 4096; ++r2) {
        int e = e0 + (r2 * 1024 + tid) * 4;
        if (e < E) {
            int4 c4 = *(const int4*)(col + e);
            int4 r4 = *(const int4*)(row + e);
            int p0 = atomicAdd(&h[c4.x >> BSHIFT], 1);
            pairs[p0] = r4.x | ((c4.x & (BNODES - 1)) << 17);
            int p1 = atomicAdd(&h[c4.y >> BSHIFT], 1);
            pairs[p1] = r4.y | ((c4.y & (BNODES - 1)) << 17);
            int p2 = atomicAdd(&h[c4.z >> BSHIFT], 1);
            pairs[p2] = r4.z | ((c4.z & (BNODES - 1)) << 17);
            int p3 = atomicAdd(&h[c4.w >> BSHIFT], 1);
            pairs[p3] = r4.w | ((c4.w & (BNODES - 1)) << 17);
        }
    }
}

// ---------------- 2: MFMA GEMM  hp_bf16 = (dinv*x) @ W  (+ zero row n) ------
// 256 thr = 4 waves; 64-row tile; wave w does rows w*16..w*16+15 x all 64 cols.
__global__ __launch_bounds__(256) void gemm_kernel(
    const float* __restrict__ x, const unsigned short* __restrict__ wbt,
    const int* __restrict__ nodecnt, unsigned short* __restrict__ hpb, int n)
{
    __shared__ __align__(16) unsigned short xl[64 * XSTR];  // 17408 B
    __shared__ __align__(16) unsigned short wl[64 * XSTR];  // W^T: [n][k]

    int tid  = threadIdx.x;
    int row0 = blockIdx.x * 64;

    {
        const uint4* src = (const uint4*)wbt;
        #pragma unroll
        for (int i = 0; i < 4; ++i) {
            int flat = tid + i * 256;
            int nn = flat >> 4, c = flat & 15;
            *(uint4*)(wl + nn * XSTR + c * 8) = src[flat];
        }
    }
    #pragma unroll
    for (int i = 0; i < 4; ++i) {
        int r  = (tid >> 4) + i * 16;
        int c  = tid & 15;
        int gr = row0 + r;
        float4 v0 = make_float4(0.f,0.f,0.f,0.f), v1 = v0;
        float d = 0.f;
        if (gr < n) {
            d = rsqrtf((float)(nodecnt[gr] + 1));     // +1 self loop
            const float4* xr = (const float4*)(x + (size_t)gr * IN_CH);
            v0 = xr[c * 2]; v1 = xr[c * 2 + 1];
        }
        uint4 p;
        p.x = ((unsigned)f2b(v0.y * d) << 16) | f2b(v0.x * d);
        p.y = ((unsigned)f2b(v0.w * d) << 16) | f2b(v0.z * d);
        p.z = ((unsigned)f2b(v1.y * d) << 16) | f2b(v1.x * d);
        p.w = ((unsigned)f2b(v1.w * d) << 16) | f2b(v1.z * d);
        *(uint4*)(xl + r * XSTR + c * 8) = p;
    }
    __syncthreads();

    int lane = tid & 63, w = tid >> 6;
    int mrow = lane & 15;
    int g    = lane >> 4;

    f32x4 acc0 = {0,0,0,0}, acc1 = {0,0,0,0}, acc2 = {0,0,0,0}, acc3 = {0,0,0,0};
    const unsigned short* xbase = xl + (w * 16 + mrow) * XSTR + g * 8;
    const unsigned short* wbase = wl + mrow * XSTR + g * 8;

    #pragma unroll
    for (int k4 = 0; k4 < 4; ++k4) {
        bf16x8 a  = *(const bf16x8*)(xbase + k4 * 32);
        bf16x8 b0 = *(const bf16x8*)(wbase +             k4 * 32);
        bf16x8 b1 = *(const bf16x8*)(wbase + 16 * XSTR + k4 * 32);
        bf16x8 b2 = *(const bf16x8*)(wbase + 32 * XSTR + k4 * 32);
        bf16x8 b3 = *(const bf16x8*)(wbase + 48 * XSTR + k4 * 32);
        acc0 = __builtin_amdgcn_mfma_f32_16x16x32_bf16(a, b0, acc0, 0, 0, 0);
        acc1 = __builtin_amdgcn_mfma_f32_16x16x32_bf16(a, b1, acc1, 0, 0, 0);
        acc2 = __builtin_amdgcn_mfma_f32_16x16x32_bf16(a, b2, acc2, 0, 0, 0);
        acc3 = __builtin_amdgcn_mfma_f32_16x16x32_bf16(a, b3, acc3, 0, 0, 0);
    }
    __syncthreads();   // done reading xl; reuse it for the C tile

    {
        int cm = g * 4;
        #pragma unroll
        for (int r = 0; r < 4; ++r) {
            unsigned short* crow = xl + (w * 16 + cm + r) * XSTR + mrow;
            crow[ 0] = f2b(acc0[r]);
            crow[16] = f2b(acc1[r]);
            crow[32] = f2b(acc2[r]);
            crow[48] = f2b(acc3[r]);
        }
    }
    __syncthreads();
    #pragma unroll
    for (int i = 0; i < 2; ++i) {
        int flat = tid + i * 256;
        int r = flat >> 3, c = flat & 7;
        int gr = row0 + r;
        if (gr <= n) {     // row n = sentinel zero row for padded aggregation
            uint4 v = *(const uint4*)(xl + r * XSTR + c * 8);
            *(uint4*)(hpb + (size_t)gr * OUT_CH + c * 8) = v;
        }
    }
}

// ---------------- 3: sortagg — in-LDS sort, aggregate from LDS --------------
// 512 thr. Phase 1: hist + scatter into sorted[128][32] (sentinel n).
// Phase 2: 8 waves x 16 nodes; per node: 32 idx via ds_read (1 row, conflict-
// free), deg from cnt[] (broadcast), guarded dwordx4 gathers (v15 body),
// stride-8 butterfly, epilogue. Overflow (deg>32): LDS list, broadcast scan.
__global__ __launch_bounds__(512) void sortagg_kernel(
    const int* __restrict__ cursor_end, const int* __restrict__ pairs,
    const unsigned short* __restrict__ hpb,
    const float* __restrict__ bias, float* __restrict__ out, int n)
{
    __shared__ int cnt[BNODES];
    __shared__ int cur[BNODES];
    __shared__ __align__(16) int sorted[SORT_CAP];   // 16 KB
    __shared__ int ovl[OVB];
    __shared__ int ovc;

    int b = blockIdx.x, tid = threadIdx.x;
    int node0 = b << BSHIFT;
    int nodeCnt = min(BNODES, n - node0);
    int s0 = b * PSTRIDE;
    int m  = cursor_end[b] - s0;

    if (tid < BNODES) { cnt[tid] = 0; cur[tid] = 0; }
    if (tid == 0) ovc = 0;
    #pragma unroll
    for (int i = 0; i < SORT_CAP / 512; ++i) sorted[tid + i * 512] = n;
    __syncthreads();
    for (int e = tid; e < m; e += 512) atomicAdd(&cnt[pairs[s0 + e] >> 17], 1);
    __syncthreads();
    for (int e = tid; e < m; e += 512) {
        int p   = pairs[s0 + e];
        int lc  = p >> 17;
        int pos = atomicAdd(&cur[lc], 1);
        if (pos < SLOTS) sorted[lc * SLOTS + pos] = p & 0x1FFFF;
        else {
            int o = atomicAdd(&ovc, 1);
            if (o < OVB) ovl[o] = p;                  // (lcol<<17)|row
        }
    }
    __syncthreads();
    int oc = min(ovc, OVB);

    // ---- phase 2: aggregate ----
    int lane = tid & 63, w = tid >> 6;     // 8 waves
    int e = lane >> 3, c = lane & 7, l31 = lane & 31;
    const uint4* hp16 = (const uint4*)hpb;

    for (int ii = 0; ii < BNODES / 8; ++ii) {
        int i = w * (BNODES / 8) + ii;
        if (i >= nodeCnt) break;                      // wave-uniform
        int node = node0 + i;

        int iv = sorted[i * SLOTS + l31];             // ds_read, bank-clean
        int dg = cnt[i];                              // LDS broadcast
        uint4 sv = hp16[(unsigned)(node * 8 + c)];    // self-loop chunk
        float d = rsqrtf((float)(dg + 1));
        int rnds = (min(dg, SLOTS) + 7) >> 3;         // 0..4, wave-uniform

        float axl=0.f,axh=0.f, ayl=0.f,ayh=0.f, azl=0.f,azh=0.f, awl=0.f,awh=0.f;

        #define GATHER(SRC) \
            { int r_ = __shfl(iv, (SRC));                                        \
              uint4 v_ = hp16[(unsigned)(r_ * 8 + c)];                           \
              axl += blo(v_.x); axh += bhi(v_.x);                                \
              ayl += blo(v_.y); ayh += bhi(v_.y);                                \
              azl += blo(v_.z); azh += bhi(v_.z);                                \
              awl += blo(v_.w); awh += bhi(v_.w); }

        if (rnds > 0) GATHER(     e)
        if (rnds > 1) GATHER( 8 + e)
        if (rnds > 2) GATHER(16 + e)
        if (rnds > 3) GATHER(24 + e)
        #undef GATHER

        if (oc > 0) {                // rare: deg>32 spill, LDS broadcast scan
            for (int o = 0; o < oc; ++o) {
                int p = ovl[o];
                if ((p >> 17) == i) {
                    uint4 v_ = hp16[(unsigned)((p & 0x1FFFF) * 8 + c)];
                    if (e == 0) {    // count once across the 8 e-slots
                        axl += blo(v_.x); axh += bhi(v_.x);
                        ayl += blo(v_.y); ayh += bhi(v_.y);
                        azl += blo(v_.z); azh += bhi(v_.z);
                        awl += blo(v_.w); awh += bhi(v_.w);
                    }
                }
            }
        }

        #pragma unroll
        for (int mm = 8; mm < 64; mm <<= 1) {
            axl += __shfl_xor(axl, mm); axh += __shfl_xor(axh, mm);
            ayl += __shfl_xor(ayl, mm); ayh += __shfl_xor(ayh, mm);
            azl += __shfl_xor(azl, mm); azh += __shfl_xor(azh, mm);
            awl += __shfl_xor(awl, mm); awh += __shfl_xor(awh, mm);
        }

        if (e == 0) {          // lanes 0..7 finalize chunk c = channels 8c..8c+7
            axl += blo(sv.x); axh += bhi(sv.x);
            ayl += blo(sv.y); ayh += bhi(sv.y);
            azl += blo(sv.z); azh += bhi(sv.z);
            awl += blo(sv.w); awh += bhi(sv.w);
            float4 b0 = ((const float4*)bias)[2 * c];
            float4 b1 = ((const float4*)bias)[2 * c + 1];
            float4 o0, o1;
            o0.x = fmaf(d, axl, b0.x); o0.y = fmaf(d, axh, b0.y);
            o0.z = fmaf(d, ayl, b0.z); o0.w = fmaf(d, ayh, b0.w);
            o1.x = fmaf(d, azl, b1.x); o1.y = fmaf(d, azh, b1.y);
            o1.z = fmaf(d, awl, b1.z); o1.w = fmaf(d, awh, b1.w);
            float* op = out + (size_t)node * OUT_CH + c * 8;
            *(float4*)op       = o0;
            *(float4*)(op + 4) = o1;
        }
    }
}

extern "C" void kernel_launch(void* const* d_in, const int* in_sizes, int n_in,
                              void* d_out, int out_size, void* d_ws, size_t ws_size,
                              hipStream_t stream) {
    const float* x  = (const float*)d_in[0];
    const int*   ei = (const int*)d_in[1];
    const float* W  = (const float*)d_in[2];
    const float* b  = (const float*)d_in[3];
    float*       out = (float*)d_out;

    int n = in_sizes[0] / IN_CH;     // 100000
    int E = in_sizes[1] / 2;         // 1600000
    const int* row = ei;
    const int* col = ei + E;

    int NB   = (n + BNODES - 1) >> BSHIFT;           // 782
    int NBLK = (E + CH_EDGES - 1) / CH_EDGES;        // 196

    // workspace layout (~33 MB of 256 MiB)
    char* ws = (char*)d_ws;
    int*   cursor  = (int*)ws;  ws += (size_t)NB * 4;
    int*   nodecnt = (int*)ws;  ws += (size_t)n * 4;
    unsigned short* wbt = (unsigned short*)ws; ws += (size_t)IN_CH * OUT_CH * 2;
    ws = (char*)(((uintptr_t)ws + 255) & ~(uintptr_t)255);
    int*   pairs   = (int*)ws;  ws += (size_t)NB * PSTRIDE * 4;   // 12.8 MB
    ws = (char*)(((uintptr_t)ws + 255) & ~(uintptr_t)255);
    unsigned short* hpb = (unsigned short*)ws;   // (n+1)*64 bf16 (row n = zeros)

    prep_kernel   <<<(n + 255) / 256, 256, 0, stream>>>(W, wbt, cursor, nodecnt, NB, n);
    place_kernel  <<<NBLK, 1024, 0, stream>>>(row, col, cursor, nodecnt, pairs, E, NB);
    gemm_kernel   <<<(n + 63) / 64, 256, 0, stream>>>(x, wbt, nodecnt, hpb, n);
    sortagg_kernel<<<NB, 512, 0, stream>>>(cursor, pairs, hpb, b, out, n);
}

// Round 11
// 172.918 us; speedup vs baseline: 1.5992x; 1.3462x over previous
//
#include <hip/hip_runtime.h>
#include <hip/hip_bf16.h>

// GCNConv: out = D^-1/2 (A+I) D^-1/2 (X W) + b
// N=100000, E=1600000, IN=128, OUT=64. edge_index int32, [row(E) | col(E)].
//
// Pipeline v18.1 — identical to v18 (R9 bench was an infra failure, resubmit):
//   0. wprep:       W fp32 [k][n] -> wbt bf16 [n][k]; cursor[b] = b*PSTRIDE
//   1. place:       LDS hist -> span reservation via atomicAdd(cursor) ->
//                   scatter pairs at fixed per-bucket stride  (v14 exact;
//                   NO global per-node atomics: v16 = dependent-atomic latency,
//                   v17 = 1.6M scattered atomics -> 61MB coherence traffic)
//   2. bucket_sort: counting sort into FIXED 32 slots/node (sentinel n pad,
//                   deg>32 -> overflow list); uint4 copy-out; degb + dinv
//   3. gemm:        MFMA 16x16x32 bf16; hp = (dinv*x) @ W; row n = zeros.
//                   fp32->bf16 via __float22bfloat162_rn (hw v_cvt_pk_bf16_f32,
//                   ~8x fewer VALU ops than manual RNE bit-twiddling)
//   4. aggregate:   wave per node (plateau'd at ~43us / 88MB FETCH: structural
//                   cross-XCD gather traffic): iv=csr line, guarded dwordx4
//                   gathers, stride-8 butterfly.

#define IN_CH 128
#define OUT_CH 64
#define BSHIFT 7            // 128 nodes per bucket
#define BNODES 128
#define MAX_NB 800
#define CH_EDGES 7168       // edges per partition block (7 rounds x 1024 thr)
#define PSTRIDE 4096        // ints per bucket in pairs (unpadded, avg 2046)
#define SLOTS 32            // fixed csr slots per node
#define SORT_CAP (BNODES * SLOTS)   // 4096 ints = 16 KB
#define OVSTRIDE 512        // per-bucket overflow capacity (deg>32 spill)
#define XSTR 136            // bf16 LDS row stride: 272B -> conflict-free b128

typedef short bf16x8 __attribute__((ext_vector_type(8)));
typedef float f32x4  __attribute__((ext_vector_type(4)));

__device__ __forceinline__ unsigned short f2b(float f) {   // RNE fp32->bf16 (hw)
    __hip_bfloat16 h = __float2bfloat16(f);
    return *(unsigned short*)&h;
}
__device__ __forceinline__ unsigned pk2(float lo, float hi) {  // packed cvt
    __hip_bfloat162 h2 = __float22bfloat162_rn(make_float2(lo, hi));
    return *(unsigned*)&h2;
}

__device__ __forceinline__ float blo(unsigned u) { return __uint_as_float(u << 16); }
__device__ __forceinline__ float bhi(unsigned u) { return __uint_as_float(u & 0xFFFF0000u); }

// ---------------- 0: W fp32 [k][n] -> bf16 [n][k]; init cursors ----------
__global__ __launch_bounds__(256) void wprep_kernel(const float* __restrict__ W,
                                                    unsigned short* __restrict__ wbt,
                                                    int* __restrict__ cursor,
                                                    int NB) {
    int t = blockIdx.x * 256 + threadIdx.x;   // 8192 threads
    int k = t >> 6, nn = t & 63;
    wbt[nn * IN_CH + k] = f2b(W[t]);
    if (t < NB) cursor[t] = t * PSTRIDE;
}

// ---------------- 1: place into pairs (LDS hist + span reservation) --------
__global__ __launch_bounds__(1024) void place_kernel(const int* __restrict__ row,
                                                     const int* __restrict__ col,
                                                     int* __restrict__ cursor,
                                                     int* __restrict__ pairs,
                                                     int E, int NB) {
    __shared__ int h[MAX_NB];
    int tid = threadIdx.x;
    for (int i = tid; i < NB; i += 1024) h[i] = 0;
    __syncthreads();
    int e0 = blockIdx.x * CH_EDGES;
    #pragma unroll
    for (int r1 = 0; r1 < CH_EDGES / 1024; ++r1) {
        int e = e0 + r1 * 1024 + tid;
        if (e < E) atomicAdd(&h[col[e] >> BSHIFT], 1);
    }
    __syncthreads();
    // reserve a contiguous span per (bucket, block); h[i] becomes local cursor
    for (int i = tid; i < NB; i += 1024) {
        int c = h[i];
        if (c) h[i] = atomicAdd(&cursor[i], c);
    }
    __syncthreads();
    #pragma unroll
    for (int r2 = 0; r2 < CH_EDGES / 1024; ++r2) {
        int e = e0 + r2 * 1024 + tid;
        if (e < E) {
            int c = col[e];
            int b = c >> BSHIFT;
            int pos = atomicAdd(&h[b], 1);            // LDS atomic
            pairs[pos] = row[e] | ((c & (BNODES - 1)) << 17);   // n < 2^17
        }
    }
}

// ---------------- 2: per-bucket counting sort into fixed 32 slots/node ------
// csr[node*32 + i]: first min(deg,32) = real source rows, rest = sentinel n.
// deg>32 spills to ovpairs[bucket*OVSTRIDE + ...] (+ ovcnt[bucket]).
// degb[node] = min(deg,255). dinv from TRUE deg.
__global__ __launch_bounds__(256) void bucket_sort_kernel(
    const int* __restrict__ cursor_end, const int* __restrict__ pairs,
    int* __restrict__ csr, int* __restrict__ ovpairs, int* __restrict__ ovcnt,
    unsigned char* __restrict__ degb, float* __restrict__ dinv, int n)
{
    __shared__ int cnt[BNODES];
    __shared__ int cur[BNODES];
    __shared__ __align__(16) int sorted[SORT_CAP];   // 16 KB
    __shared__ int ovl[OVSTRIDE];      // 2 KB
    __shared__ int ovc;

    int b = blockIdx.x, tid = threadIdx.x;
    int node0 = b << BSHIFT;
    int nodeCnt = min(BNODES, n - node0);
    int s0 = b * PSTRIDE;
    int m  = cursor_end[b] - s0;

    if (tid < BNODES) { cnt[tid] = 0; cur[tid] = 0; }
    if (tid == 0) ovc = 0;
    __syncthreads();
    for (int e = tid; e < m; e += 256) atomicAdd(&cnt[pairs[s0 + e] >> 17], 1);
    // sentinel prefill (independent of histogram)
    #pragma unroll
    for (int i = 0; i < SORT_CAP / 256; ++i) sorted[tid + i * 256] = n;
    __syncthreads();
    if (tid < nodeCnt) {
        int d = cnt[tid];
        degb[node0 + tid] = (unsigned char)min(d, 255);
        dinv[node0 + tid] = rsqrtf((float)(d + 1));   // +1 self loop
    }
    __syncthreads();
    for (int e = tid; e < m; e += 256) {
        int p   = pairs[s0 + e];
        int lc  = p >> 17;
        int pos = atomicAdd(&cur[lc], 1);
        if (pos < SLOTS) sorted[lc * SLOTS + pos] = p & 0x1FFFF;
        else {
            int o = atomicAdd(&ovc, 1);
            if (o < OVSTRIDE) ovl[o] = p;             // (lcol<<17)|row
        }
    }
    __syncthreads();
    {   // coalesced copy-out: 16 KB as uint4 (4x fewer instructions)
        uint4* dst = (uint4*)(csr + node0 * SLOTS);
        const uint4* src = (const uint4*)sorted;
        #pragma unroll
        for (int i = 0; i < SORT_CAP / 1024; ++i)
            dst[tid + i * 256] = src[tid + i * 256];
    }
    int oc = min(ovc, OVSTRIDE);
    if (tid == 0) ovcnt[b] = oc;
    for (int i = tid; i < oc; i += 256) ovpairs[b * OVSTRIDE + i] = ovl[i];
}

// ---------------- 3: MFMA GEMM  hp_bf16 = (dinv*x) @ W  (+ zero row n) ------
// 256 thr = 4 waves; 64-row tile; wave w does rows w*16..w*16+15 x all 64 cols.
__global__ __launch_bounds__(256) void gemm_kernel(
    const float* __restrict__ x, const unsigned short* __restrict__ wbt,
    const float* __restrict__ dinv, unsigned short* __restrict__ hpb, int n)
{
    __shared__ __align__(16) unsigned short xl[64 * XSTR];  // 17408 B
    __shared__ __align__(16) unsigned short wl[64 * XSTR];  // W^T: [n][k]

    int tid  = threadIdx.x;
    int row0 = blockIdx.x * 64;

    {
        const uint4* src = (const uint4*)wbt;
        #pragma unroll
        for (int i = 0; i < 4; ++i) {
            int flat = tid + i * 256;
            int nn = flat >> 4, c = flat & 15;
            *(uint4*)(wl + nn * XSTR + c * 8) = src[flat];
        }
    }
    #pragma unroll
    for (int i = 0; i < 4; ++i) {
        int r  = (tid >> 4) + i * 16;
        int c  = tid & 15;
        int gr = row0 + r;
        float4 v0 = make_float4(0.f,0.f,0.f,0.f), v1 = v0;
        float d = 0.f;
        if (gr < n) {
            d = dinv[gr];
            const float4* xr = (const float4*)(x + (size_t)gr * IN_CH);
            v0 = xr[c * 2]; v1 = xr[c * 2 + 1];
        }
        uint4 p;                       // hw packed cvt: v_cvt_pk_bf16_f32
        p.x = pk2(v0.x * d, v0.y * d);
        p.y = pk2(v0.z * d, v0.w * d);
        p.z = pk2(v1.x * d, v1.y * d);
        p.w = pk2(v1.z * d, v1.w * d);
        *(uint4*)(xl + r * XSTR + c * 8) = p;
    }
    __syncthreads();

    int lane = tid & 63, w = tid >> 6;
    int mrow = lane & 15;
    int g    = lane >> 4;

    f32x4 acc0 = {0,0,0,0}, acc1 = {0,0,0,0}, acc2 = {0,0,0,0}, acc3 = {0,0,0,0};
    const unsigned short* xbase = xl + (w * 16 + mrow) * XSTR + g * 8;
    const unsigned short* wbase = wl + mrow * XSTR + g * 8;

    #pragma unroll
    for (int k4 = 0; k4 < 4; ++k4) {
        bf16x8 a  = *(const bf16x8*)(xbase + k4 * 32);
        bf16x8 b0 = *(const bf16x8*)(wbase +             k4 * 32);
        bf16x8 b1 = *(const bf16x8*)(wbase + 16 * XSTR + k4 * 32);
        bf16x8 b2 = *(const bf16x8*)(wbase + 32 * XSTR + k4 * 32);
        bf16x8 b3 = *(const bf16x8*)(wbase + 48 * XSTR + k4 * 32);
        acc0 = __builtin_amdgcn_mfma_f32_16x16x32_bf16(a, b0, acc0, 0, 0, 0);
        acc1 = __builtin_amdgcn_mfma_f32_16x16x32_bf16(a, b1, acc1, 0, 0, 0);
        acc2 = __builtin_amdgcn_mfma_f32_16x16x32_bf16(a, b2, acc2, 0, 0, 0);
        acc3 = __builtin_amdgcn_mfma_f32_16x16x32_bf16(a, b3, acc3, 0, 0, 0);
    }
    __syncthreads();   // done reading xl; reuse it for the C tile

    {
        int cm = g * 4;
        #pragma unroll
        for (int r = 0; r < 4; ++r) {
            unsigned short* crow = xl + (w * 16 + cm + r) * XSTR + mrow;
            crow[ 0] = f2b(acc0[r]);
            crow[16] = f2b(acc1[r]);
            crow[32] = f2b(acc2[r]);
            crow[48] = f2b(acc3[r]);
        }
    }
    __syncthreads();
    #pragma unroll
    for (int i = 0; i < 2; ++i) {
        int flat = tid + i * 256;
        int r = flat >> 3, c = flat & 7;
        int gr = row0 + r;
        if (gr <= n) {     // row n = sentinel zero row for padded aggregation
            uint4 v = *(const uint4*)(xl + r * XSTR + c * 8);
            *(uint4*)(hpb + (size_t)gr * OUT_CH + c * 8) = v;
        }
    }
}

// ---------------- 4: aggregate — wave/node, guarded gathers, fixed-32 -------
// lane = (e = edge slot 0..7, c = 16B chunk 0..7).
// iv = csr[wid*32 + (lane&31)] : ONE 128B line; self/dinv/deg issue in
// parallel (no dependent chain). Gather g uses rows shfl(iv, g*8+e), guarded
// by wave-uniform rnds = ceil(min(deg,32)/8) -> no sentinel gathers.
__global__ __launch_bounds__(256) void aggregate_kernel(
    const int* __restrict__ csr, const int* __restrict__ ovpairs,
    const int* __restrict__ ovcnt, const unsigned char* __restrict__ degb,
    const unsigned short* __restrict__ hpb, const float* __restrict__ dinv,
    const float* __restrict__ bias, float* __restrict__ out, int n)
{
    int wid  = (blockIdx.x * 256 + threadIdx.x) >> 6;   // node id
    int lane = threadIdx.x & 63;
    if (wid >= n) return;
    int e   = lane >> 3;
    int c   = lane & 7;
    int l31 = lane & 31;

    const uint4* hp16 = (const uint4*)hpb;   // row = 8 x uint4

    // independent loads — all issue before any dependency:
    int iv = csr[wid * SLOTS + l31];
    float d = dinv[wid];
    int deg = degb[wid];
    int bno = wid >> BSHIFT;
    int oc  = ovcnt[bno];
    uint4 sv = hp16[(unsigned)(wid * 8 + c)];           // self-loop chunk (1 line)

    int rnds = (min(deg, SLOTS) + 7) >> 3;              // 0..4, wave-uniform

    float axl=0.f,axh=0.f, ayl=0.f,ayh=0.f, azl=0.f,azh=0.f, awl=0.f,awh=0.f;

    #define GATHER(SRC) \
        { int r_ = __shfl(iv, (SRC));                                            \
          uint4 v_ = hp16[(unsigned)(r_ * 8 + c)];                               \
          axl += blo(v_.x); axh += bhi(v_.x);                                    \
          ayl += blo(v_.y); ayh += bhi(v_.y);                                    \
          azl += blo(v_.z); azh += bhi(v_.z);                                    \
          awl += blo(v_.w); awh += bhi(v_.w); }

    if (rnds > 0) GATHER(     e)
    if (rnds > 1) GATHER( 8 + e)
    if (rnds > 2) GATHER(16 + e)
    if (rnds > 3) GATHER(24 + e)
    #undef GATHER

    if (oc > 0) {                     // rare (deg>32 spill), wave-uniform
        const int* op = ovpairs + bno * OVSTRIDE;
        for (int i = 0; i < oc; ++i) {
            int p    = op[i];
            int node = (bno << BSHIFT) + (p >> 17);
            if (node == wid) {
                uint4 v = hp16[(unsigned)((p & 0x1FFFF) * 8 + c)];
                if (e == 0) {         // count once across the 8 e-slots
                    axl += blo(v.x); axh += bhi(v.x); ayl += blo(v.y); ayh += bhi(v.y);
                    azl += blo(v.z); azh += bhi(v.z); awl += blo(v.w); awh += bhi(v.w);
                }
            }
        }
    }

    // reduce across the 8 edge slots (lanes c, c+8, ..., c+56)
    #pragma unroll
    for (int m = 8; m < 64; m <<= 1) {
        axl += __shfl_xor(axl, m); axh += __shfl_xor(axh, m);
        ayl += __shfl_xor(ayl, m); ayh += __shfl_xor(ayh, m);
        azl += __shfl_xor(azl, m); azh += __shfl_xor(azh, m);
        awl += __shfl_xor(awl, m); awh += __shfl_xor(awh, m);
    }

    if (e == 0) {              // lanes 0..7 finalize chunk c = channels 8c..8c+7
        axl += blo(sv.x); axh += bhi(sv.x);
        ayl += blo(sv.y); ayh += bhi(sv.y);
        azl += blo(sv.z); azh += bhi(sv.z);
        awl += blo(sv.w); awh += bhi(sv.w);
        float4 b0 = ((const float4*)bias)[2 * c];
        float4 b1 = ((const float4*)bias)[2 * c + 1];
        float4 o0, o1;
        o0.x = fmaf(d, axl, b0.x); o0.y = fmaf(d, axh, b0.y);
        o0.z = fmaf(d, ayl, b0.z); o0.w = fmaf(d, ayh, b0.w);
        o1.x = fmaf(d, azl, b1.x); o1.y = fmaf(d, azh, b1.y);
        o1.z = fmaf(d, awl, b1.z); o1.w = fmaf(d, awh, b1.w);
        float* op = out + (size_t)wid * OUT_CH + c * 8;
        *(float4*)op       = o0;
        *(float4*)(op + 4) = o1;
    }
}

extern "C" void kernel_launch(void* const* d_in, const int* in_sizes, int n_in,
                              void* d_out, int out_size, void* d_ws, size_t ws_size,
                              hipStream_t stream) {
    const float* x  = (const float*)d_in[0];
    const int*   ei = (const int*)d_in[1];
    const float* W  = (const float*)d_in[2];
    const float* b  = (const float*)d_in[3];
    float*       out = (float*)d_out;

    int n = in_sizes[0] / IN_CH;     // 100000
    int E = in_sizes[1] / 2;         // 1600000
    const int* row = ei;
    const int* col = ei + E;

    int NB   = (n + BNODES - 1) >> BSHIFT;           // 782
    int NBLK = (E + CH_EDGES - 1) / CH_EDGES;        // 224

    // workspace layout (~45 MB of 256 MiB)
    char* ws = (char*)d_ws;
    int*   cursor       = (int*)ws;   ws += (size_t)NB * 4;
    int*   ovcnt        = (int*)ws;   ws += (size_t)NB * 4;
    float* dinv         = (float*)ws; ws += (size_t)n * 4;
    unsigned char* degb = (unsigned char*)ws; ws += (size_t)(n + 2) & ~1ull; ws = (char*)(((uintptr_t)ws + 255) & ~(uintptr_t)255);
    unsigned short* wbt = (unsigned short*)ws; ws += (size_t)IN_CH * OUT_CH * 2;
    ws = (char*)(((uintptr_t)ws + 255) & ~(uintptr_t)255);
    int*   pairs        = (int*)ws;   ws += (size_t)NB * PSTRIDE * 4;   // 12.8 MB
    int*   ovpairs      = (int*)ws;   ws += (size_t)NB * OVSTRIDE * 4;  //  1.6 MB
    int*   csr          = (int*)ws;   ws += (size_t)NB * BNODES * SLOTS * 4; // 12.8 MB
    unsigned short* hpb = (unsigned short*)ws;   // (n+1)*64 bf16 (row n = zeros)

    wprep_kernel      <<<(IN_CH * OUT_CH) / 256, 256, 0, stream>>>(W, wbt, cursor, NB);
    place_kernel      <<<NBLK, 1024, 0, stream>>>(row, col, cursor, pairs, E, NB);
    bucket_sort_kernel<<<NB, 256, 0, stream>>>(cursor, pairs, csr, ovpairs, ovcnt, degb, dinv, n);
    gemm_kernel       <<<(n + 63) / 64, 256, 0, stream>>>(x, wbt, dinv, hpb, n);
    aggregate_kernel  <<<((size_t)n * 64 + 255) / 256, 256, 0, stream>>>(csr, ovpairs, ovcnt, degb, hpb, dinv, b, out, n);
}

// Round 12
// 168.905 us; speedup vs baseline: 1.6372x; 1.0238x over previous
//
#include <hip/hip_runtime.h>
#include <hip/hip_bf16.h>

// GCNConv: out = D^-1/2 (A+I) D^-1/2 (X W) + b
// N=100000, E=1600000, IN=128, OUT=64. edge_index int32, [row(E) | col(E)].
//
// Pipeline v19 == v14 verbatim (best measured: 167.99us). Consolidation round:
// v15/v18 micro-opts (int4 place, uint4 copy-out, hw bf16 intrinsics) each
// correlated with small regressions (HIP bf16 intrinsics carry NaN-handling
// branches; deltas within +-3us noise) — reverting to the measured optimum.
//   0. wprep:       W fp32 [k][n] -> wbt bf16 [n][k]; cursor[b] = b*PSTRIDE
//   1. place:       LDS hist -> span reservation via atomicAdd(cursor) ->
//                   scatter pairs at fixed per-bucket stride
//   2. bucket_sort: counting sort into FIXED 32 slots/node (sentinel n pad;
//                   deg>32 spills to per-bucket overflow list); deg byte+dinv
//   3. gemm:        MFMA 16x16x32 bf16; hp_bf16 = (dinv[row]*x) @ W; row n = 0
//   4. aggregate:   wave per NODE PAIR (2w,2w+1): one 64-lane index load
//                   covers both adjacent segments; up to 8 independent dwordx4
//                   gathers in flight, wave-uniform ceil(deg/8) guards.
//                   Plateau: 42.4-43.5us / ~88MB FETCH across 7 structural
//                   variants = random-128B-line HBM limit (12.8MB hp table
//                   gathered 1.6M times across 8 non-coherent XCD L2s).

#define IN_CH 128
#define OUT_CH 64
#define BSHIFT 7            // 128 nodes per bucket
#define BNODES 128
#define MAX_NB 800
#define CH_EDGES 7168       // edges per partition block (7 rounds x 1024 thr)
#define PSTRIDE 4096        // ints per bucket in pairs (unpadded, avg 2046)
#define SLOTS 32            // fixed csr slots per node
#define SORT_CAP (BNODES * SLOTS)   // 4096 ints = 16 KB
#define OVSTRIDE 512        // per-bucket overflow capacity (deg>32 spill)
#define XSTR 136            // bf16 LDS row stride: 272B -> conflict-free b128

typedef short bf16x8 __attribute__((ext_vector_type(8)));
typedef float f32x4  __attribute__((ext_vector_type(4)));

__device__ __forceinline__ unsigned short f2b(float f) {   // RNE fp32->bf16
    unsigned int u = __float_as_uint(f);
    return (unsigned short)((u + 0x7FFFu + ((u >> 16) & 1u)) >> 16);
}

__device__ __forceinline__ float blo(unsigned u) { return __uint_as_float(u << 16); }
__device__ __forceinline__ float bhi(unsigned u) { return __uint_as_float(u & 0xFFFF0000u); }

// ---------------- 0: W fp32 [k][n] -> bf16 [n][k]; init cursors ----------
__global__ __launch_bounds__(256) void wprep_kernel(const float* __restrict__ W,
                                                    unsigned short* __restrict__ wbt,
                                                    int* __restrict__ cursor,
                                                    int NB) {
    int t = blockIdx.x * 256 + threadIdx.x;   // 8192 threads
    int k = t >> 6, nn = t & 63;
    wbt[nn * IN_CH + k] = f2b(W[t]);
    if (t < NB) cursor[t] = t * PSTRIDE;
}

// ---------------- 1: place into pairs (LDS hist + span reservation) --------
__global__ __launch_bounds__(1024) void place_kernel(const int* __restrict__ row,
                                                     const int* __restrict__ col,
                                                     int* __restrict__ cursor,
                                                     int* __restrict__ pairs,
                                                     int E, int NB) {
    __shared__ int h[MAX_NB];
    int tid = threadIdx.x;
    for (int i = tid; i < NB; i += 1024) h[i] = 0;
    __syncthreads();
    int e0 = blockIdx.x * CH_EDGES;
    #pragma unroll
    for (int r1 = 0; r1 < CH_EDGES / 1024; ++r1) {
        int e = e0 + r1 * 1024 + tid;
        if (e < E) atomicAdd(&h[col[e] >> BSHIFT], 1);
    }
    __syncthreads();
    // reserve a contiguous span per (bucket, block); h[i] becomes local cursor
    for (int i = tid; i < NB; i += 1024) {
        int c = h[i];
        if (c) h[i] = atomicAdd(&cursor[i], c);
    }
    __syncthreads();
    #pragma unroll
    for (int r2 = 0; r2 < CH_EDGES / 1024; ++r2) {
        int e = e0 + r2 * 1024 + tid;
        if (e < E) {
            int c = col[e];
            int b = c >> BSHIFT;
            int pos = atomicAdd(&h[b], 1);            // LDS atomic
            pairs[pos] = row[e] | ((c & (BNODES - 1)) << 17);   // n < 2^17
        }
    }
}

// ---------------- 2: per-bucket counting sort into fixed 32 slots/node ------
// csr[node*32 + i]: first min(deg,32) = real source rows, rest = sentinel n.
// deg>32 spills to ovpairs[bucket*OVSTRIDE + ...] (+ ovcnt[bucket]).
// degb[node] = min(deg,255) (Poisson(16): max ~50). dinv from TRUE deg.
__global__ __launch_bounds__(256) void bucket_sort_kernel(
    const int* __restrict__ cursor_end, const int* __restrict__ pairs,
    int* __restrict__ csr, int* __restrict__ ovpairs, int* __restrict__ ovcnt,
    unsigned char* __restrict__ degb, float* __restrict__ dinv, int n)
{
    __shared__ int cnt[BNODES];
    __shared__ int cur[BNODES];
    __shared__ int sorted[SORT_CAP];   // 16 KB
    __shared__ int ovl[OVSTRIDE];      // 2 KB
    __shared__ int ovc;

    int b = blockIdx.x, tid = threadIdx.x;
    int node0 = b << BSHIFT;
    int nodeCnt = min(BNODES, n - node0);
    int s0 = b * PSTRIDE;
    int m  = cursor_end[b] - s0;

    if (tid < BNODES) { cnt[tid] = 0; cur[tid] = 0; }
    if (tid == 0) ovc = 0;
    __syncthreads();
    for (int e = tid; e < m; e += 256) atomicAdd(&cnt[pairs[s0 + e] >> 17], 1);
    // sentinel prefill (independent of histogram)
    #pragma unroll
    for (int i = 0; i < SORT_CAP / 256; ++i) sorted[tid + i * 256] = n;
    __syncthreads();
    if (tid < nodeCnt) {
        int d = cnt[tid];
        degb[node0 + tid] = (unsigned char)min(d, 255);
        dinv[node0 + tid] = rsqrtf((float)(d + 1));   // +1 self loop
    }
    __syncthreads();
    for (int e = tid; e < m; e += 256) {
        int p   = pairs[s0 + e];
        int lc  = p >> 17;
        int pos = atomicAdd(&cur[lc], 1);
        if (pos < SLOTS) sorted[lc * SLOTS + pos] = p & 0x1FFFF;
        else {
            int o = atomicAdd(&ovc, 1);
            if (o < OVSTRIDE) ovl[o] = p;             // (lcol<<17)|row
        }
    }
    __syncthreads();
    {   // coalesced copy-out: 16 KB
        int base = node0 * SLOTS;
        #pragma unroll
        for (int i = 0; i < SORT_CAP / 256; ++i)
            csr[base + tid + i * 256] = sorted[tid + i * 256];
    }
    int oc = min(ovc, OVSTRIDE);
    if (tid == 0) ovcnt[b] = oc;
    for (int i = tid; i < oc; i += 256) ovpairs[b * OVSTRIDE + i] = ovl[i];
}

// ---------------- 3: MFMA GEMM  hp_bf16 = (dinv*x) @ W  (+ zero row n) ------
// 256 thr = 4 waves; 64-row tile; wave w does rows w*16..w*16+15 x all 64 cols.
__global__ __launch_bounds__(256) void gemm_kernel(
    const float* __restrict__ x, const unsigned short* __restrict__ wbt,
    const float* __restrict__ dinv, unsigned short* __restrict__ hpb, int n)
{
    __shared__ __align__(16) unsigned short xl[64 * XSTR];  // 17408 B
    __shared__ __align__(16) unsigned short wl[64 * XSTR];  // W^T: [n][k]

    int tid  = threadIdx.x;
    int row0 = blockIdx.x * 64;

    {
        const uint4* src = (const uint4*)wbt;
        #pragma unroll
        for (int i = 0; i < 4; ++i) {
            int flat = tid + i * 256;
            int nn = flat >> 4, c = flat & 15;
            *(uint4*)(wl + nn * XSTR + c * 8) = src[flat];
        }
    }
    #pragma unroll
    for (int i = 0; i < 4; ++i) {
        int r  = (tid >> 4) + i * 16;
        int c  = tid & 15;
        int gr = row0 + r;
        float4 v0 = make_float4(0.f,0.f,0.f,0.f), v1 = v0;
        float d = 0.f;
        if (gr < n) {
            d = dinv[gr];
            const float4* xr = (const float4*)(x + (size_t)gr * IN_CH);
            v0 = xr[c * 2]; v1 = xr[c * 2 + 1];
        }
        uint4 p;
        p.x = ((unsigned)f2b(v0.y * d) << 16) | f2b(v0.x * d);
        p.y = ((unsigned)f2b(v0.w * d) << 16) | f2b(v0.z * d);
        p.z = ((unsigned)f2b(v1.y * d) << 16) | f2b(v1.x * d);
        p.w = ((unsigned)f2b(v1.w * d) << 16) | f2b(v1.z * d);
        *(uint4*)(xl + r * XSTR + c * 8) = p;
    }
    __syncthreads();

    int lane = tid & 63, w = tid >> 6;
    int mrow = lane & 15;
    int g    = lane >> 4;

    f32x4 acc0 = {0,0,0,0}, acc1 = {0,0,0,0}, acc2 = {0,0,0,0}, acc3 = {0,0,0,0};
    const unsigned short* xbase = xl + (w * 16 + mrow) * XSTR + g * 8;
    const unsigned short* wbase = wl + mrow * XSTR + g * 8;

    #pragma unroll
    for (int k4 = 0; k4 < 4; ++k4) {
        bf16x8 a  = *(const bf16x8*)(xbase + k4 * 32);
        bf16x8 b0 = *(const bf16x8*)(wbase +             k4 * 32);
        bf16x8 b1 = *(const bf16x8*)(wbase + 16 * XSTR + k4 * 32);
        bf16x8 b2 = *(const bf16x8*)(wbase + 32 * XSTR + k4 * 32);
        bf16x8 b3 = *(const bf16x8*)(wbase + 48 * XSTR + k4 * 32);
        acc0 = __builtin_amdgcn_mfma_f32_16x16x32_bf16(a, b0, acc0, 0, 0, 0);
        acc1 = __builtin_amdgcn_mfma_f32_16x16x32_bf16(a, b1, acc1, 0, 0, 0);
        acc2 = __builtin_amdgcn_mfma_f32_16x16x32_bf16(a, b2, acc2, 0, 0, 0);
        acc3 = __builtin_amdgcn_mfma_f32_16x16x32_bf16(a, b3, acc3, 0, 0, 0);
    }
    __syncthreads();   // done reading xl; reuse it for the C tile

    {
        int cm = g * 4;
        #pragma unroll
        for (int r = 0; r < 4; ++r) {
            unsigned short* crow = xl + (w * 16 + cm + r) * XSTR + mrow;
            crow[ 0] = f2b(acc0[r]);
            crow[16] = f2b(acc1[r]);
            crow[32] = f2b(acc2[r]);
            crow[48] = f2b(acc3[r]);
        }
    }
    __syncthreads();
    #pragma unroll
    for (int i = 0; i < 2; ++i) {
        int flat = tid + i * 256;
        int r = flat >> 3, c = flat & 7;
        int gr = row0 + r;
        if (gr <= n) {     // row n = sentinel zero row for padded aggregation
            uint4 v = *(const uint4*)(xl + r * XSTR + c * 8);
            *(uint4*)(hpb + (size_t)gr * OUT_CH + c * 8) = v;
        }
    }
}

// ---------------- 4: aggregate — node pair per wave, fixed-32 segments ------
// lane = (e = edge slot 0..7, c = 16B chunk 0..7). Nodes A=2w, B=2w+1.
// iv = csr[A*32 + lane]: lanes 0-31 = A's slots, 32-63 = B's slots.
// Gather g for A: rows shfl(iv, g*8+e); for B: shfl(iv, 32+g*8+e).
// Wave-uniform guards skip all-sentinel gathers (rnds = ceil(min(deg,32)/8)).
__global__ __launch_bounds__(256) void aggregate_kernel(
    const int* __restrict__ csr, const int* __restrict__ ovpairs,
    const int* __restrict__ ovcnt, const unsigned char* __restrict__ degb,
    const unsigned short* __restrict__ hpb, const float* __restrict__ dinv,
    const float* __restrict__ bias, float* __restrict__ out, int n)
{
    int pw   = (blockIdx.x * 256 + threadIdx.x) >> 6;   // pair id
    int lane = threadIdx.x & 63;
    int A = 2 * pw, B = A + 1;
    if (A >= n) return;                                 // n even -> B < n
    int e = lane >> 3;
    int c = lane & 7;

    const uint4* hp16 = (const uint4*)hpb;   // row = 8 x uint4

    // all independent loads issue in parallel (no dependent chain before iv):
    int iv = csr[A * SLOTS + lane];
    float2 dd = ((const float2*)dinv)[pw];
    unsigned short ds = ((const unsigned short*)degb)[pw];
    int bno = A >> BSHIFT;
    int oc  = ovcnt[bno];
    int srow = (lane & 8) ? B : A;                       // lanes 0-7:A, 8-15:B
    uint4 sv = hp16[(unsigned)(srow * 8 + c)];           // self-loop chunk

    int degA = ds & 255, degB = ds >> 8;
    int rA = (min(degA, SLOTS) + 7) >> 3;                // 0..4
    int rB = (min(degB, SLOTS) + 7) >> 3;

    float axl=0.f,axh=0.f, ayl=0.f,ayh=0.f, azl=0.f,azh=0.f, awl=0.f,awh=0.f;  // A
    float bxl=0.f,bxh=0.f, byl=0.f,byh=0.f, bzl=0.f,bzh=0.f, bwl=0.f,bwh=0.f;  // B

    #define GATHER(ACC_XL,ACC_XH,ACC_YL,ACC_YH,ACC_ZL,ACC_ZH,ACC_WL,ACC_WH, SRC) \
        { int r_ = __shfl(iv, (SRC));                                            \
          uint4 v_ = hp16[(unsigned)(r_ * 8 + c)];                               \
          ACC_XL += blo(v_.x); ACC_XH += bhi(v_.x);                              \
          ACC_YL += blo(v_.y); ACC_YH += bhi(v_.y);                              \
          ACC_ZL += blo(v_.z); ACC_ZH += bhi(v_.z);                              \
          ACC_WL += blo(v_.w); ACC_WH += bhi(v_.w); }

    // wave-uniform guards; loads within taken guards issue back-to-back
    if (rA > 0) GATHER(axl,axh,ayl,ayh,azl,azh,awl,awh,      e)
    if (rB > 0) GATHER(bxl,bxh,byl,byh,bzl,bzh,bwl,bwh, 32 + e)
    if (rA > 1) GATHER(axl,axh,ayl,ayh,azl,azh,awl,awh,  8 + e)
    if (rB > 1) GATHER(bxl,bxh,byl,byh,bzl,bzh,bwl,bwh, 40 + e)
    if (rA > 2) GATHER(axl,axh,ayl,ayh,azl,azh,awl,awh, 16 + e)
    if (rB > 2) GATHER(bxl,bxh,byl,byh,bzl,bzh,bwl,bwh, 48 + e)
    if (rA > 3) GATHER(axl,axh,ayl,ayh,azl,azh,awl,awh, 24 + e)
    if (rB > 3) GATHER(bxl,bxh,byl,byh,bzl,bzh,bwl,bwh, 56 + e)
    #undef GATHER

    if (oc > 0) {                     // rare (deg>32 spill), wave-uniform
        const int* op = ovpairs + bno * OVSTRIDE;
        for (int i = 0; i < oc; ++i) {
            int p    = op[i];
            int node = (bno << BSHIFT) + (p >> 17);
            if (node == A || node == B) {
                uint4 v = hp16[(unsigned)((p & 0x1FFFF) * 8 + c)];
                if (e == 0) {         // count once across the 8 e-slots
                    if (node == A) {
                        axl += blo(v.x); axh += bhi(v.x); ayl += blo(v.y); ayh += bhi(v.y);
                        azl += blo(v.z); azh += bhi(v.z); awl += blo(v.w); awh += bhi(v.w);
                    } else {
                        bxl += blo(v.x); bxh += bhi(v.x); byl += blo(v.y); byh += bhi(v.y);
                        bzl += blo(v.z); bzh += bhi(v.z); bwl += blo(v.w); bwh += bhi(v.w);
                    }
                }
            }
        }
    }

    // reduce across the 8 edge slots (lanes c, c+8, ..., c+56)
    #pragma unroll
    for (int m = 8; m < 64; m <<= 1) {
        axl += __shfl_xor(axl, m); axh += __shfl_xor(axh, m);
        ayl += __shfl_xor(ayl, m); ayh += __shfl_xor(ayh, m);
        azl += __shfl_xor(azl, m); azh += __shfl_xor(azh, m);
        awl += __shfl_xor(awl, m); awh += __shfl_xor(awh, m);
        bxl += __shfl_xor(bxl, m); bxh += __shfl_xor(bxh, m);
        byl += __shfl_xor(byl, m); byh += __shfl_xor(byh, m);
        bzl += __shfl_xor(bzl, m); bzh += __shfl_xor(bzh, m);
        bwl += __shfl_xor(bwl, m); bwh += __shfl_xor(bwh, m);
    }

    if (lane < 16) {                  // lanes 0-7 finalize A, 8-15 finalize B
        int   node = srow;            // matches sv
        float d    = (lane & 8) ? dd.y : dd.x;
        float sxl, sxh, syl, syh, szl, szh, swl, swh;
        if (lane & 8) { sxl=bxl; sxh=bxh; syl=byl; syh=byh; szl=bzl; szh=bzh; swl=bwl; swh=bwh; }
        else          { sxl=axl; sxh=axh; syl=ayl; syh=ayh; szl=azl; szh=azh; swl=awl; swh=awh; }
        sxl += blo(sv.x); sxh += bhi(sv.x);
        syl += blo(sv.y); syh += bhi(sv.y);
        szl += blo(sv.z); szh += bhi(sv.z);
        swl += blo(sv.w); swh += bhi(sv.w);
        float4 b0 = ((const float4*)bias)[2 * c];
        float4 b1 = ((const float4*)bias)[2 * c + 1];
        float4 o0, o1;
        o0.x = fmaf(d, sxl, b0.x); o0.y = fmaf(d, sxh, b0.y);
        o0.z = fmaf(d, syl, b0.z); o0.w = fmaf(d, syh, b0.w);
        o1.x = fmaf(d, szl, b1.x); o1.y = fmaf(d, szh, b1.y);
        o1.z = fmaf(d, swl, b1.z); o1.w = fmaf(d, swh, b1.w);
        float* op = out + (size_t)node * OUT_CH + c * 8;
        *(float4*)op       = o0;
        *(float4*)(op + 4) = o1;
    }
}

extern "C" void kernel_launch(void* const* d_in, const int* in_sizes, int n_in,
                              void* d_out, int out_size, void* d_ws, size_t ws_size,
                              hipStream_t stream) {
    const float* x  = (const float*)d_in[0];
    const int*   ei = (const int*)d_in[1];
    const float* W  = (const float*)d_in[2];
    const float* b  = (const float*)d_in[3];
    float*       out = (float*)d_out;

    int n = in_sizes[0] / IN_CH;     // 100000
    int E = in_sizes[1] / 2;         // 1600000
    const int* row = ei;
    const int* col = ei + E;

    int NB   = (n + BNODES - 1) >> BSHIFT;           // 782
    int NBLK = (E + CH_EDGES - 1) / CH_EDGES;        // 224

    // workspace layout (~45 MB of 256 MiB)
    char* ws = (char*)d_ws;
    int*   cursor       = (int*)ws;   ws += (size_t)NB * 4;
    int*   ovcnt        = (int*)ws;   ws += (size_t)NB * 4;
    float* dinv         = (float*)ws; ws += (size_t)n * 4;
    unsigned char* degb = (unsigned char*)ws; ws += (size_t)(n + 2) & ~1ull; ws = (char*)(((uintptr_t)ws + 255) & ~(uintptr_t)255);
    unsigned short* wbt = (unsigned short*)ws; ws += (size_t)IN_CH * OUT_CH * 2;
    ws = (char*)(((uintptr_t)ws + 255) & ~(uintptr_t)255);
    int*   pairs        = (int*)ws;   ws += (size_t)NB * PSTRIDE * 4;   // 12.8 MB
    int*   ovpairs      = (int*)ws;   ws += (size_t)NB * OVSTRIDE * 4;  //  1.6 MB
    int*   csr          = (int*)ws;   ws += (size_t)NB * BNODES * SLOTS * 4; // 12.8 MB
    unsigned short* hpb = (unsigned short*)ws;   // (n+1)*64 bf16 (row n = zeros)

    wprep_kernel      <<<(IN_CH * OUT_CH) / 256, 256, 0, stream>>>(W, wbt, cursor, NB);
    place_kernel      <<<NBLK, 1024, 0, stream>>>(row, col, cursor, pairs, E, NB);
    bucket_sort_kernel<<<NB, 256, 0, stream>>>(cursor, pairs, csr, ovpairs, ovcnt, degb, dinv, n);
    gemm_kernel       <<<(n + 63) / 64, 256, 0, stream>>>(x, wbt, dinv, hpb, n);
    aggregate_kernel  <<<(n / 2 * 64 + 255) / 256, 256, 0, stream>>>(csr, ovpairs, ovcnt, degb, hpb, dinv, b, out, n);
}